// Round 16
// baseline (24.547 us; speedup 1.0000x reference)
//
#include <hip/hip_runtime.h>
#include <hip/hip_bf16.h>

// Decompose: algebraically a single 5x5 conv with scalar taps
//   a_k = wS_k . wE_k, bias = sum_k (wS_k . bE_k + bS_k)
//   out = clip( (sum a_k * xp[h+i,w+j] + bias)/25, 0, 1 ),  xp = reflect-pad(clip(x,0,1),2)
//
// R16: global_load_lds staging + counted vmcnt (never 0), zero barriers.
// R7-R15 lesson: a VGPR-register pipeline never materializes (allocator
// pins VGPR~68, loads get sunk -> ~800cyc stall/row-iter regardless of
// structure). global_load_lds decouples in-flight depth from registers:
// each wave stages rows into its PRIVATE LDS region (consumption never
// crosses waves -> no __syncthreads; sync is per-wave s_waitcnt vmcnt(N)
// with per-iteration constant N, loads stay in flight across iters).
// Per row/wave: width16 gload (cols s-2..s+253, per-lane src) + width4
// tail (cols s+254..s+257; per-lane src implements right-edge reflect).
// Left-edge reflect = 1-lane LDS fixup. 8 slots x 1280B x 4 waves = 40KB.

#define HH 1024
#define WW 1024
#define NIMG 12
#define TBH 16             // output rows per block
#define ROWS (TBH + 4)     // 20 input rows touched
#define PF 6               // staged rows in flight
#define SLOTB 1280         // bytes per wave-slot (1024 main + 256 tail)
#define NSLOT 8

typedef float f32x4 __attribute__((ext_vector_type(4)));
typedef float f32x2 __attribute__((ext_vector_type(2)));

__device__ __forceinline__ float readlane_f(float v, int lane) {
    return __int_as_float(__builtin_amdgcn_readlane(__float_as_int(v), lane));
}
__device__ __forceinline__ float sgpr_bcast(float v) {
    return __int_as_float(__builtin_amdgcn_readfirstlane(__float_as_int(v)));
}
__device__ __forceinline__ float dot4(f32x4 a, f32x4 b) {
    return a.x * b.x + a.y * b.y + a.z * b.z + a.w * b.w;
}
__device__ __forceinline__ f32x4 clip01v4(f32x4 v) {
    f32x4 z = {0.f, 0.f, 0.f, 0.f};
    f32x4 o = {1.f, 1.f, 1.f, 1.f};
    return __builtin_elementwise_min(__builtin_elementwise_max(v, z), o);
}
__device__ __forceinline__ f32x2 clip01v2(f32x2 v) {
    f32x2 z = {0.f, 0.f};
    f32x2 o = {1.f, 1.f};
    return __builtin_elementwise_min(__builtin_elementwise_max(v, z), o);
}

#define VMWAIT(n) asm volatile("s_waitcnt vmcnt(" #n ")" ::: "memory")

__global__ __launch_bounds__(256) void conv5_kernel(const float* __restrict__ x,
                                                    const float* __restrict__ wE,
                                                    const float* __restrict__ bE,
                                                    const float* __restrict__ wS,
                                                    const float* __restrict__ bS,
                                                    float* __restrict__ out) {
    int tid  = threadIdx.x;
    int lane = tid & 63;
    int wave = tid >> 6;

    __shared__ __align__(16) char lds[4 * NSLOT * SLOTB];   // 40 KB

    // ---- Lane-parallel constant prep (per wave, redundant; ~300 cyc) ----
    float apass[2], cacc = 0.f;
    #pragma unroll
    for (int p = 0; p < 2; ++p) {
        int k = p * 16 + (lane >> 2);
        float a = 0.f;
        if (k < 25) {
            int base = k * 64 + (lane & 3) * 16;
            #pragma unroll
            for (int i = 0; i < 4; ++i) {
                f32x4 sv = *(const f32x4*)(wS + base + 4 * i);
                f32x4 ev = *(const f32x4*)(wE + base + 4 * i);
                f32x4 bv = *(const f32x4*)(bE + base + 4 * i);
                a += dot4(sv, ev);
                cacc += dot4(sv, bv);
            }
        }
        a += __shfl_xor(a, 1);
        a += __shfl_xor(a, 2);
        apass[p] = a;
    }
    if (lane < 25) cacc += bS[lane];
    #pragma unroll
    for (int off = 32; off; off >>= 1) cacc += __shfl_xor(cacc, off);
    float bias = sgpr_bcast(cacc * (1.f / 25.f));
    f32x2 bias2 = {bias, bias};

    float wv[25];
    #pragma unroll
    for (int k = 0; k < 16; ++k) wv[k] = readlane_f(apass[0], 4 * k) * (1.f / 25.f);
    #pragma unroll
    for (int k = 16; k < 25; ++k) wv[k] = readlane_f(apass[1], 4 * (k - 16)) * (1.f / 25.f);

    // ---- Tile mapping: XCD-aware bijective swizzle (768 % 8 == 0) ----
    int nwg = gridDim.x;
    int cpx = nwg >> 3;
    int l = (blockIdx.x & 7) * cpx + (blockIdx.x >> 3);
    int img = l >> 6;                         // 64 row-blocks per image
    int rb = l & 63;
    int row0 = rb * TBH;

    const float* src = x + (size_t)img * (HH * WW);
    int s = wave << 8;                        // wave strip base col
    int cbase = s + 4 * lane;                 // own cols [cbase..cbase+3]
    bool img_lt = (s == 0);
    bool img_rt = (s + 256 == WW);

    // Per-lane global column offsets (loop-invariant).
    // Main width16: region floats f = 4*lane .. 4*lane+3 <-> cols s-2+4*lane ..
    int coff_main = (img_lt && lane == 0) ? 0 : (s - 2 + 4 * lane);
    // Tail width4: region floats 256..259 <-> cols s+254..s+257 (lanes 0..3);
    // right-edge reflect baked into per-lane sources; lanes>=4 load a valid dummy.
    int coff_tail;
    if (img_rt) coff_tail = (lane == 1) ? 1023 : ((lane == 3) ? 1021 : 1022);
    else {
        coff_tail = s + 254 + lane;
        if (coff_tail > WW - 1) coff_tail = WW - 1;
    }

    char* lwbase = lds + wave * (NSLOT * SLOTB);

    // Row pointer with vertical reflection (block-uniform scalar math).
    auto rowptr = [&](int ir) -> const float* {
        int prow = row0 - 2 + ir;
        int sr = prow < 0 ? -prow : (prow >= HH ? 2 * HH - 2 - prow : prow);
        return src + (size_t)sr * WW;
    };

    auto stage = [&](int r) {
        const float* rp = rowptr(r);
        char* lb = lwbase + (r & (NSLOT - 1)) * SLOTB;
        __builtin_amdgcn_global_load_lds((const float*)(rp + coff_main),
                                         (float*)lb, 16, 0, 0);
        __builtin_amdgcn_global_load_lds((const float*)(rp + coff_tail),
                                         (float*)(lb + 1024), 4, 0, 0);
    };

    f32x2 acc[5][2];
    float* op = out + (size_t)img * (HH * WW) + (size_t)row0 * WW + cbase;

    // ---- Prologue: stage rows 0..PF-1 (12 gloads in flight) ----
    #pragma unroll
    for (int r = 0; r < PF; ++r) stage(r);

#define BODY(ir, vn) {                                                        \
    if ((ir) + PF < ROWS) stage((ir) + PF);                                   \
    VMWAIT(vn);                                                               \
    __builtin_amdgcn_sched_barrier(0);                                        \
    char* lb = lwbase + ((ir) & (NSLOT - 1)) * SLOTB;                         \
    if (img_lt && lane == 0) {      /* left-edge reflect fixup, 1 lane */     \
        f32x4 t = *(f32x4*)lb;      /* staged x0,x1,x2,x3 */                  \
        f32x4 w4 = {t.z, t.y, t.x, t.y};  /* want x2,x1,x0,x1 */              \
        *(f32x4*)lb = w4;                                                     \
    }                                                                         \
    f32x4 u = *(f32x4*)(lb + 16 * lane);                                      \
    f32x4 v = *(f32x4*)(lb + 16 * lane + 16);                                 \
    u = clip01v4(u);                                                          \
    v = clip01v4(v);                                                          \
    float r8[8] = {u.x, u.y, u.z, u.w, v.x, v.y, v.z, v.w};                   \
    f32x2 pr[7];                                                              \
    _Pragma("unroll")                                                         \
    for (int j = 0; j < 7; ++j) { pr[j].x = r8[j]; pr[j].y = r8[j + 1]; }     \
    if ((ir) < TBH) { acc[(ir) % 5][0] = bias2; acc[(ir) % 5][1] = bias2; }   \
    _Pragma("unroll")                                                         \
    for (int dr = 0; dr < 5; ++dr) {                                          \
        int orow = (ir) - dr;                                                 \
        if (orow >= 0 && orow < TBH) {                                        \
            _Pragma("unroll")                                                 \
            for (int j = 0; j < 5; ++j) {                                     \
                float wj = wv[dr * 5 + j];                                    \
                f32x2 w2 = {wj, wj};                                          \
                acc[orow % 5][0] += pr[j] * w2;                               \
                acc[orow % 5][1] += pr[j + 2] * w2;                           \
            }                                                                 \
        }                                                                     \
    }                                                                         \
    if ((ir) >= 4) {                                                          \
        int orow = (ir) - 4;                                                  \
        f32x2 lo = clip01v2(acc[orow % 5][0]);                                \
        f32x2 hi = clip01v2(acc[orow % 5][1]);                                \
        f32x4 o = {lo.x, lo.y, hi.x, hi.y};                                   \
        *(f32x4*)(op + (size_t)orow * WW) = o;                                \
    }                                                                         \
}

    // vmcnt(N): N = 2*min(PF, 19-ir) younger gloads (stores excluded ->
    // mild over-wait, always safe; loads never drained to 0 until the end).
    BODY(0, 12)  BODY(1, 12)  BODY(2, 12)  BODY(3, 12)  BODY(4, 12)
    BODY(5, 12)  BODY(6, 12)  BODY(7, 12)  BODY(8, 12)  BODY(9, 12)
    BODY(10, 12) BODY(11, 12) BODY(12, 12) BODY(13, 12) BODY(14, 10)
    BODY(15, 8)  BODY(16, 6)  BODY(17, 4)  BODY(18, 2)  BODY(19, 0)
#undef BODY
}

extern "C" void kernel_launch(void* const* d_in, const int* in_sizes, int n_in,
                              void* d_out, int out_size, void* d_ws, size_t ws_size,
                              hipStream_t stream) {
    const float* x  = (const float*)d_in[0];
    const float* wE = (const float*)d_in[1];
    const float* bE = (const float*)d_in[2];
    const float* wS = (const float*)d_in[3];
    const float* bS = (const float*)d_in[4];
    float* out = (float*)d_out;

    int nblocks = NIMG * (HH / TBH);   // 12 * 64 = 768
    conv5_kernel<<<nblocks, 256, 0, stream>>>(x, wE, bE, wS, bS, out);
}